// Round 4
// baseline (1468.201 us; speedup 1.0000x reference)
//
#include <hip/hip_runtime.h>
#include <cstdint>
#include <cstddef>

#define E_EXP 8
#define TOPK 2
#define DMODEL 512
#define DFFDIM 2048

typedef __attribute__((ext_vector_type(8))) short short8;
typedef __attribute__((ext_vector_type(4))) float f32x4;

__device__ __forceinline__ unsigned short f2bf(float f) {
    unsigned int u = __float_as_uint(f);
    u += 0x7fffu + ((u >> 16) & 1u);   // round-to-nearest-even
    return (unsigned short)(u >> 16);
}

// async global->LDS, 16B per lane. LDS dest MUST be wave-uniform; HW writes lane i
// at base + i*16 (m104). Caller passes an in-bounds, wave-uniform LDS pointer.
__device__ __forceinline__ void gld_lds16(const unsigned short* g, unsigned short* l) {
    __builtin_amdgcn_global_load_lds(
        (const __attribute__((address_space(1))) void*)g,
        (__attribute__((address_space(3))) void*)l, 16, 0, 0);
}

// ---------------- weight transpose + fp32->bf16 convert ----------------
// in: [E][R][C] fp32  ->  out: [E][C][R] bf16
__global__ __launch_bounds__(256) void transpose_kernel(
    const float* __restrict__ in, unsigned short* __restrict__ out, int R, int C)
{
    __shared__ float tile[32][33];
    const float* ie = in + (size_t)blockIdx.z * R * C;
    unsigned short* oe = out + (size_t)blockIdx.z * R * C;
    int x = blockIdx.x * 32 + threadIdx.x;
#pragma unroll
    for (int i = 0; i < 4; i++) {
        int ry = blockIdx.y * 32 + threadIdx.y + i * 8;
        tile[threadIdx.y + i * 8][threadIdx.x] = ie[(size_t)ry * C + x];
    }
    __syncthreads();
    int xo = blockIdx.y * 32 + threadIdx.x;
#pragma unroll
    for (int i = 0; i < 4; i++) {
        int co = blockIdx.x * 32 + threadIdx.y + i * 8;
        oe[(size_t)co * R + xo] = f2bf(tile[threadIdx.x][threadIdx.y + i * 8]);
    }
}

// ---------------- router: logits -> softmax -> top2 -> weights ----------------
__global__ __launch_bounds__(256) void router_kernel(
    const float* __restrict__ x, const float* __restrict__ Wr,
    const float* __restrict__ br, int N,
    int* __restrict__ e0e1, float2* __restrict__ w01)
{
    int lane = threadIdx.x & 63, wave = threadIdx.x >> 6;
    int t = blockIdx.x * 4 + wave;
    if (t >= N) return;
    const float* xr = x + (size_t)t * DMODEL;
    float4 v0 = *(const float4*)(xr + lane * 4);
    float4 v1 = *(const float4*)(xr + 256 + lane * 4);
    float xv[8] = {v0.x, v0.y, v0.z, v0.w, v1.x, v1.y, v1.z, v1.w};
    const float* wr0 = Wr + (size_t)lane * 32;             // rows lane*4 .. +3
    const float* wr1 = Wr + (size_t)(256 + lane * 4) * 8;  // rows 256+lane*4 .. +3
    double acc[8];
#pragma unroll
    for (int j = 0; j < 8; j++) acc[j] = 0.0;
#pragma unroll
    for (int c = 0; c < 4; c++) {
#pragma unroll
        for (int j = 0; j < 8; j++) {
            acc[j] += (double)xv[c] * (double)wr0[c * 8 + j];
            acc[j] += (double)xv[4 + c] * (double)wr1[c * 8 + j];
        }
    }
#pragma unroll
    for (int j = 0; j < 8; j++) {
        double s = acc[j];
#pragma unroll
        for (int o = 32; o > 0; o >>= 1) s += __shfl_xor(s, o, 64);
        acc[j] = s;
    }
    if (lane == 0) {
        float l[8], p[8];
        float mx = -1e30f;
        for (int j = 0; j < 8; j++) { l[j] = (float)acc[j] + br[j]; mx = fmaxf(mx, l[j]); }
        float Z = 0.f;
        for (int j = 0; j < 8; j++) { p[j] = expf(l[j] - mx); Z += p[j]; }
        for (int j = 0; j < 8; j++) p[j] /= Z;
        int e0 = 0;
        for (int j = 1; j < 8; j++) if (l[j] > l[e0]) e0 = j;        // ties -> lower idx
        int e1 = (e0 == 0) ? 1 : 0;
        for (int j = 0; j < 8; j++) if (j != e0 && l[j] > l[e1]) e1 = j;
        float den = p[e0] + p[e1] + 1e-9f;
        e0e1[t] = e0 | (e1 << 8);
        w01[t] = make_float2(p[e0] / den, p[e1] / den);
    }
}

// ---------------- per-block expert histogram (slot order) ----------------
__global__ __launch_bounds__(256) void hist_kernel(
    const int* __restrict__ e0e1, int NK, int* __restrict__ hist)
{
    __shared__ int cnt[8];
    int t = threadIdx.x;
    if (t < 8) cnt[t] = 0;
    __syncthreads();
    int s = blockIdx.x * 256 + t;
    if (s < NK) {
        int pk = e0e1[s >> 1];
        int e = (s & 1) ? ((pk >> 8) & 255) : (pk & 255);
        atomicAdd(&cnt[e], 1);
    }
    __syncthreads();
    if (t < 8) hist[blockIdx.x * 8 + t] = cnt[t];
}

// ---------------- scan histogram -> per-block bases + used counts ----------------
__global__ __launch_bounds__(256) void scan_kernel(
    const int* __restrict__ hist, int NB, int cap,
    int* __restrict__ base, int* __restrict__ cnt_used)
{
    __shared__ int buf[256];
    int t = threadIdx.x;
    for (int e = 0; e < 8; e++) {
        int v = (t < NB) ? hist[t * 8 + e] : 0;
        int val = v;
        buf[t] = val;
        __syncthreads();
        for (int o = 1; o < 256; o <<= 1) {
            int add = (t >= o) ? buf[t - o] : 0;
            __syncthreads();
            val += add;
            buf[t] = val;
            __syncthreads();
        }
        if (t < NB) base[t * 8 + e] = val - v;     // exclusive prefix
        if (t == 255) cnt_used[e] = min(val, cap); // total, clamped to capacity
        __syncthreads();
    }
}

// ---------------- positions, capacity drop, weight renorm, slot->token maps ----------------
__global__ __launch_bounds__(256) void pos_kernel(
    const int* __restrict__ e0e1, const float2* __restrict__ w01,
    const int* __restrict__ base, int NK, int cap,
    int* __restrict__ sidx, int* __restrict__ tok_of, float* __restrict__ wslot)
{
    __shared__ int waveCnt[4][8];
    __shared__ float kw[256];
    int t = threadIdx.x, lane = t & 63, wave = t >> 6;
    int s = blockIdx.x * 256 + t;
    bool valid = s < NK;
    int e = 8; float w = 0.f;
    if (valid) {
        int pk = e0e1[s >> 1];
        float2 ww = w01[s >> 1];
        if (s & 1) { e = (pk >> 8) & 255; w = ww.y; }
        else       { e = pk & 255;        w = ww.x; }
    }
    unsigned long long mymask = 0ull;
#pragma unroll
    for (int j = 0; j < 8; j++) {
        unsigned long long m = __ballot(e == j);
        if (lane == j) waveCnt[wave][j] = __popcll(m);
        if (e == j) mymask = m;
    }
    __syncthreads();
    int wrank = __popcll(mymask & ((1ull << lane) - 1ull));
    int prior = 0;
    for (int w2 = 0; w2 < wave; w2++) prior += waveCnt[w2][e & 7];
    int pos = base[blockIdx.x * 8 + (e & 7)] + prior + wrank;
    bool keep = valid && (pos < cap);
    kw[t] = keep ? w : 0.f;
    __syncthreads();
    float sum = kw[t] + kw[t ^ 1];      // the 2 slots of a token are adjacent
    float wn = keep ? (kw[t] / (sum + 1e-9f)) : 0.f;
    if (valid) {
        int si = keep ? (e * cap + pos) : -1;
        sidx[s] = si;
        if (keep) { tok_of[si] = s >> 1; wslot[si] = wn; }
    }
}

// ---------------- scatter tokens into expert buffers (fp32 -> bf16) ----------------
__global__ __launch_bounds__(256) void scatter_kernel(
    const float* __restrict__ x, const int* __restrict__ sidx,
    unsigned short* __restrict__ Xe, int NK)
{
    int lane = threadIdx.x & 63, wave = threadIdx.x >> 6;
    int s = blockIdx.x * 4 + wave;
    if (s >= NK) return;
    int si = sidx[s];
    if (si < 0) return;
    int tok = s >> 1;
    const float* xr = x + (size_t)tok * DMODEL + lane * 8;
    float4 a = *(const float4*)xr;
    float4 b = *(const float4*)(xr + 4);
    short8 v;
    v[0] = (short)f2bf(a.x); v[1] = (short)f2bf(a.y);
    v[2] = (short)f2bf(a.z); v[3] = (short)f2bf(a.w);
    v[4] = (short)f2bf(b.x); v[5] = (short)f2bf(b.y);
    v[6] = (short)f2bf(b.z); v[7] = (short)f2bf(b.w);
    *(short8*)(Xe + (size_t)si * DMODEL + lane * 8) = v;
}

// ---------------- grouped GEMM: 256x256 tile, BK=64, 8 waves, dbuf global_load_lds ----
// All 8 experts in one dispatch (z = expert). T3-minimum 2-phase: STAGE(next) issued
// BEFORE compute(cur); one drain-barrier per k-step; loads fly under the 64 MFMAs.
// LDS rows are 64 bf16 = 128 B; linear would be 16-way bank conflict on ds_read_b128.
// Swizzle (rule #21, both-sides-or-neither): LDS slot (row, s) holds global seg
// s ^ (row&7); staging pre-swizzles the GLOBAL source seg (dest stays HW-linear);
// reader XORs the same involution -> 2-way (free) on reads, linear (free) on writes.
// MODE 0: out(bf16) = GELU(A*B^T + bias), row stride ldc
// MODE 1: atomicAdd into y: y[tok_of[slot]] += wslot[slot] * (A*B^T [+ bias if addBias])
template <int MODE>
__global__ __launch_bounds__(512, 2) void gemm256_kernel(
    const unsigned short* __restrict__ A, int lda, size_t aStrE,
    const unsigned short* __restrict__ B, int ldb, size_t bStrE,
    const float* __restrict__ bias, int biasStrE,
    void* __restrict__ out, size_t cStrE, int ldc,
    const int* __restrict__ cnt, const int* __restrict__ tok_of,
    const float* __restrict__ wslot, int cap, int Kext, int addBias)
{
    // 2 buffers x 256 rows x 64 bf16 per array = 2 x 32 KB x 2 arrays = 128 KB LDS
    __shared__ unsigned short As[2 * 16384];
    __shared__ unsigned short Bs[2 * 16384];
    int e = blockIdx.z;
    int m0 = blockIdx.y * 256, n0 = blockIdx.x * 256;
    int M = cnt[e];
    if (m0 >= M) return;   // tile entirely beyond this expert's row count
    const unsigned short* Ae = A + (size_t)e * aStrE;
    const unsigned short* Be = B + (size_t)e * bStrE;

    int t = threadIdx.x, lane = t & 63, wave = t >> 6;
    // staging: thread t stages slot (u*512 + t) of each 2048-slot (256row x 8seg) tile
    int srow = t >> 3;                         // row within each 64-row group
    int gseg = ((t & 7) ^ (srow & 7)) * 8;     // pre-swizzled global seg (elements)
    const unsigned short* ga = Ae + (size_t)(m0 + srow) * lda + gseg;
    const unsigned short* gb = Be + (size_t)(n0 + srow) * ldb + gseg;
    // wave-uniform LDS stripe base (ushorts): wave w owns slots [64w, 64w+64) per group
    int wofs = __builtin_amdgcn_readfirstlane(wave * 512);

    f32x4 acc[8][4];
#pragma unroll
    for (int i = 0; i < 8; i++)
#pragma unroll
        for (int j = 0; j < 4; j++) acc[i][j] = (f32x4){0.f, 0.f, 0.f, 0.f};

    // wave tile: 2M x 4N -> per-wave 128(M) x 64(N)
    int wm = (wave >> 2) * 128, wn = (wave & 3) * 64;
    int lr = lane & 15, lq = lane >> 4;
    int s0 = ((lq) ^ (lr & 7)) * 8;            // k-half 0 swizzled seg (elements)
    int s1 = ((lq + 4) ^ (lr & 7)) * 8;        // k-half 1
    const unsigned short* pa = As + (wm + lr) * 64;
    const unsigned short* pb = Bs + (wn + lr) * 64;

    const int nt = Kext >> 6;                  // k-steps of 64

    // prologue: stage k-tile 0 into buffer 0
#pragma unroll
    for (int u = 0; u < 4; u++) {
        gld_lds16(ga + (size_t)(u * 64) * lda, As + u * 4096 + wofs);
        gld_lds16(gb + (size_t)(u * 64) * ldb, Bs + u * 4096 + wofs);
    }
    __syncthreads();

    int buf = 0;
    for (int ks = 1; ks < nt; ks++) {
        // issue next k-tile stage into the other buffer (flies under the MFMAs)
        int nbo = (buf ^ 1) * 16384;
        int k0 = ks * 64;
#pragma unroll
        for (int u = 0; u < 4; u++) {
            gld_lds16(ga + (size_t)(u * 64) * lda + k0, As + nbo + u * 4096 + wofs);
            gld_lds16(gb + (size_t)(u * 64) * ldb + k0, Bs + nbo + u * 4096 + wofs);
        }
        // compute current buffer: 2 k-halves x (8 M-frags x 4 N-frags)
        {
            int bo = buf * 16384;
            short8 af[8], bfv[4];
#pragma unroll
            for (int i = 0; i < 8; i++) af[i] = *(const short8*)(pa + bo + i * 1024 + s0);
#pragma unroll
            for (int j = 0; j < 4; j++) bfv[j] = *(const short8*)(pb + bo + j * 1024 + s0);
#pragma unroll
            for (int i = 0; i < 8; i++)
#pragma unroll
                for (int j = 0; j < 4; j++)
                    acc[i][j] = __builtin_amdgcn_mfma_f32_16x16x32_bf16(af[i], bfv[j], acc[i][j], 0, 0, 0);
#pragma unroll
            for (int i = 0; i < 8; i++) af[i] = *(const short8*)(pa + bo + i * 1024 + s1);
#pragma unroll
            for (int j = 0; j < 4; j++) bfv[j] = *(const short8*)(pb + bo + j * 1024 + s1);
#pragma unroll
            for (int i = 0; i < 8; i++)
#pragma unroll
                for (int j = 0; j < 4; j++)
                    acc[i][j] = __builtin_amdgcn_mfma_f32_16x16x32_bf16(af[i], bfv[j], acc[i][j], 0, 0, 0);
        }
        __syncthreads();   // drains vmcnt(0): next buffer staged; all reads of buf done
        buf ^= 1;
    }
    // last k-tile compute
    {
        int bo = buf * 16384;
        short8 af[8], bfv[4];
#pragma unroll
        for (int i = 0; i < 8; i++) af[i] = *(const short8*)(pa + bo + i * 1024 + s0);
#pragma unroll
        for (int j = 0; j < 4; j++) bfv[j] = *(const short8*)(pb + bo + j * 1024 + s0);
#pragma unroll
        for (int i = 0; i < 8; i++)
#pragma unroll
            for (int j = 0; j < 4; j++)
                acc[i][j] = __builtin_amdgcn_mfma_f32_16x16x32_bf16(af[i], bfv[j], acc[i][j], 0, 0, 0);
#pragma unroll
        for (int i = 0; i < 8; i++) af[i] = *(const short8*)(pa + bo + i * 1024 + s1);
#pragma unroll
        for (int j = 0; j < 4; j++) bfv[j] = *(const short8*)(pb + bo + j * 1024 + s1);
#pragma unroll
        for (int i = 0; i < 8; i++)
#pragma unroll
            for (int j = 0; j < 4; j++)
                acc[i][j] = __builtin_amdgcn_mfma_f32_16x16x32_bf16(af[i], bfv[j], acc[i][j], 0, 0, 0);
    }

    // epilogue; C/D layout: col=lane&15, row=(lane>>4)*4+r
    if (MODE == 0) {
        size_t cb = (size_t)e * cStrE;
#pragma unroll
        for (int j = 0; j < 4; j++) {
            int n = n0 + wn + j * 16 + lr;
            float bv = bias[(size_t)e * biasStrE + n];
#pragma unroll
            for (int i = 0; i < 8; i++) {
                int mbase = m0 + wm + i * 16 + lq * 4;
                f32x4 v = acc[i][j];
#pragma unroll
                for (int r = 0; r < 4; r++) {
                    float val = v[r] + bv;
                    val = 0.5f * val * (1.0f + erff(val * 0.7071067811865475f));
                    ((unsigned short*)out)[cb + (size_t)(mbase + r) * ldc + n] = f2bf(val);
                }
            }
        }
    } else {
        float wv[8][4]; int tv[8][4];
#pragma unroll
        for (int i = 0; i < 8; i++) {
            int mbase = m0 + wm + i * 16 + lq * 4;
#pragma unroll
            for (int r = 0; r < 4; r++) {
                int m = mbase + r;
                if (m < M) { int sl = e * cap + m; wv[i][r] = wslot[sl]; tv[i][r] = tok_of[sl]; }
                else       { wv[i][r] = 0.f; tv[i][r] = -1; }
            }
        }
        float* y = (float*)out;
#pragma unroll
        for (int j = 0; j < 4; j++) {
            int n = n0 + wn + j * 16 + lr;
            float bv = addBias ? bias[(size_t)e * biasStrE + n] : 0.f;
#pragma unroll
            for (int i = 0; i < 8; i++) {
                f32x4 v = acc[i][j];
#pragma unroll
                for (int r = 0; r < 4; r++) {
                    if (tv[i][r] >= 0)
                        atomicAdd(y + (size_t)tv[i][r] * ldc + n, wv[i][r] * (v[r] + bv));
                }
            }
        }
    }
}

extern "C" void kernel_launch(void* const* d_in, const int* in_sizes, int n_in,
                              void* d_out, int out_size, void* d_ws, size_t ws_size,
                              hipStream_t stream)
{
    const float* x  = (const float*)d_in[0];
    const float* Wr = (const float*)d_in[1];
    const float* br = (const float*)d_in[2];
    const float* W1 = (const float*)d_in[3];
    const float* b1 = (const float*)d_in[4];
    const float* W2 = (const float*)d_in[5];
    const float* b2 = (const float*)d_in[6];
    float* y = (float*)d_out;
    (void)n_in; (void)ws_size;

    const int N = in_sizes[0] / DMODEL;            // 32768 tokens
    const int NK = N * TOPK;                       // 65536 slots
    const int cap = (NK * 5 + 31) / 32;            // ceil(1.25*NK/8) = 10240
    const int mT = (cap + 255) / 256;              // 40
    const int NB = (NK + 255) / 256;               // 256
    const int QD = DFFDIM / 4;                     // 512: DFF quarter width

    char* ws = (char*)d_ws;
    size_t off = 0;
    auto take = [&](size_t bytes) {
        char* p = ws + off;
        off = (off + bytes + 255) & ~(size_t)255;
        return p;
    };
    unsigned short* W1t = (unsigned short*)take((size_t)E_EXP * DMODEL * DFFDIM * 2); // [E][DFF][D]
    unsigned short* W2t = (unsigned short*)take((size_t)E_EXP * DMODEL * DFFDIM * 2); // [E][D][DFF]
    unsigned short* Xe  = (unsigned short*)take((size_t)E_EXP * cap * DMODEL * 2);    // expert_in bf16
    unsigned short* Hg  = (unsigned short*)take((size_t)E_EXP * cap * QD * 2);        // hidden, DFF-quarter, all experts
    int*    e0e1 = (int*)take((size_t)N * 4);
    float2* w01  = (float2*)take((size_t)N * 8);
    int*    hist = (int*)take((size_t)NB * 8 * 4);
    int*    base = (int*)take((size_t)NB * 8 * 4);
    int*    cnt  = (int*)take(64);
    int*    sidx = (int*)take((size_t)NK * 4);
    int*    tok_of = (int*)take((size_t)E_EXP * cap * 4);
    float*  wslot  = (float*)take((size_t)E_EXP * cap * 4);

    transpose_kernel<<<dim3(DFFDIM / 32, DMODEL / 32, E_EXP), dim3(32, 8), 0, stream>>>(W1, W1t, DMODEL, DFFDIM);
    transpose_kernel<<<dim3(DMODEL / 32, DFFDIM / 32, E_EXP), dim3(32, 8), 0, stream>>>(W2, W2t, DFFDIM, DMODEL);
    router_kernel<<<(N + 3) / 4, 256, 0, stream>>>(x, Wr, br, N, e0e1, w01);
    hist_kernel<<<NB, 256, 0, stream>>>(e0e1, NK, hist);
    scan_kernel<<<1, 256, 0, stream>>>(hist, NB, cap, base, cnt);
    pos_kernel<<<NB, 256, 0, stream>>>(e0e1, w01, base, NK, cap, sidx, tok_of, wslot);
    scatter_kernel<<<(NK + 3) / 4, 256, 0, stream>>>(x, sidx, Xe, NK);
    hipMemsetAsync(d_out, 0, (size_t)out_size * 4, stream);

    // DFF processed in 4 quarters so Hg for ALL 8 experts fits the workspace:
    // each pair of dispatches runs 640 blocks (all experts) -> full-chip parallelism.
    for (int q = 0; q < 4; q++) {
        // GEMM1(q): Hg[e][:, 0:512] = GELU(Xe[e] * W1t[e][q*512:(q+1)*512]^T + b1), K=512
        gemm256_kernel<0><<<dim3(QD / 256, mT, E_EXP), 512, 0, stream>>>(
            Xe, DMODEL, (size_t)cap * DMODEL,
            W1t + (size_t)q * QD * DMODEL, DMODEL, (size_t)DFFDIM * DMODEL,
            b1 + q * QD, DFFDIM,
            Hg, (size_t)cap * QD, QD,
            cnt, tok_of, wslot, cap, DMODEL, 1);
        // GEMM2(q): y[tok] += wslot * (Hg[e] * W2t[e][:, q*512:(q+1)*512]^T [+ b2 if q==0])
        gemm256_kernel<1><<<dim3(DMODEL / 256, mT, E_EXP), 512, 0, stream>>>(
            Hg, QD, (size_t)cap * QD,
            W2t + (size_t)q * QD, DFFDIM, (size_t)DMODEL * DFFDIM,
            b2, DMODEL,
            y, 0, DMODEL,
            cnt, tok_of, wslot, cap, QD, q == 0 ? 1 : 0);
    }
}

// Round 5
// 1074.538 us; speedup vs baseline: 1.3664x; 1.3664x over previous
//
#include <hip/hip_runtime.h>
#include <cstdint>
#include <cstddef>

#define E_EXP 8
#define TOPK 2
#define DMODEL 512
#define DFFDIM 2048

typedef __attribute__((ext_vector_type(8))) short short8;
typedef __attribute__((ext_vector_type(4))) float f32x4;

__device__ __forceinline__ unsigned short f2bf(float f) {
    unsigned int u = __float_as_uint(f);
    u += 0x7fffu + ((u >> 16) & 1u);   // round-to-nearest-even
    return (unsigned short)(u >> 16);
}

// async global->LDS, 16B per lane. LDS dest MUST be wave-uniform; HW writes lane i
// at base + i*16 (m104). Caller passes an in-bounds, wave-uniform LDS pointer.
__device__ __forceinline__ void gld_lds16(const unsigned short* g, unsigned short* l) {
    __builtin_amdgcn_global_load_lds(
        (const __attribute__((address_space(1))) void*)g,
        (__attribute__((address_space(3))) void*)l, 16, 0, 0);
}

// ---------------- weight transpose + fp32->bf16 convert ----------------
// in: [E][R][C] fp32  ->  out: [E][C][R] bf16
__global__ __launch_bounds__(256) void transpose_kernel(
    const float* __restrict__ in, unsigned short* __restrict__ out, int R, int C)
{
    __shared__ float tile[32][33];
    const float* ie = in + (size_t)blockIdx.z * R * C;
    unsigned short* oe = out + (size_t)blockIdx.z * R * C;
    int x = blockIdx.x * 32 + threadIdx.x;
#pragma unroll
    for (int i = 0; i < 4; i++) {
        int ry = blockIdx.y * 32 + threadIdx.y + i * 8;
        tile[threadIdx.y + i * 8][threadIdx.x] = ie[(size_t)ry * C + x];
    }
    __syncthreads();
    int xo = blockIdx.y * 32 + threadIdx.x;
#pragma unroll
    for (int i = 0; i < 4; i++) {
        int co = blockIdx.x * 32 + threadIdx.y + i * 8;
        oe[(size_t)co * R + xo] = f2bf(tile[threadIdx.x][threadIdx.y + i * 8]);
    }
}

// ---------------- router: logits -> softmax -> top2 -> weights ----------------
__global__ __launch_bounds__(256) void router_kernel(
    const float* __restrict__ x, const float* __restrict__ Wr,
    const float* __restrict__ br, int N,
    int* __restrict__ e0e1, float2* __restrict__ w01)
{
    int lane = threadIdx.x & 63, wave = threadIdx.x >> 6;
    int t = blockIdx.x * 4 + wave;
    if (t >= N) return;
    const float* xr = x + (size_t)t * DMODEL;
    float4 v0 = *(const float4*)(xr + lane * 4);
    float4 v1 = *(const float4*)(xr + 256 + lane * 4);
    float xv[8] = {v0.x, v0.y, v0.z, v0.w, v1.x, v1.y, v1.z, v1.w};
    const float* wr0 = Wr + (size_t)lane * 32;             // rows lane*4 .. +3
    const float* wr1 = Wr + (size_t)(256 + lane * 4) * 8;  // rows 256+lane*4 .. +3
    double acc[8];
#pragma unroll
    for (int j = 0; j < 8; j++) acc[j] = 0.0;
#pragma unroll
    for (int c = 0; c < 4; c++) {
#pragma unroll
        for (int j = 0; j < 8; j++) {
            acc[j] += (double)xv[c] * (double)wr0[c * 8 + j];
            acc[j] += (double)xv[4 + c] * (double)wr1[c * 8 + j];
        }
    }
#pragma unroll
    for (int j = 0; j < 8; j++) {
        double s = acc[j];
#pragma unroll
        for (int o = 32; o > 0; o >>= 1) s += __shfl_xor(s, o, 64);
        acc[j] = s;
    }
    if (lane == 0) {
        float l[8], p[8];
        float mx = -1e30f;
        for (int j = 0; j < 8; j++) { l[j] = (float)acc[j] + br[j]; mx = fmaxf(mx, l[j]); }
        float Z = 0.f;
        for (int j = 0; j < 8; j++) { p[j] = expf(l[j] - mx); Z += p[j]; }
        for (int j = 0; j < 8; j++) p[j] /= Z;
        int e0 = 0;
        for (int j = 1; j < 8; j++) if (l[j] > l[e0]) e0 = j;        // ties -> lower idx
        int e1 = (e0 == 0) ? 1 : 0;
        for (int j = 0; j < 8; j++) if (j != e0 && l[j] > l[e1]) e1 = j;
        float den = p[e0] + p[e1] + 1e-9f;
        e0e1[t] = e0 | (e1 << 8);
        w01[t] = make_float2(p[e0] / den, p[e1] / den);
    }
}

// ---------------- per-block expert histogram (slot order) ----------------
__global__ __launch_bounds__(256) void hist_kernel(
    const int* __restrict__ e0e1, int NK, int* __restrict__ hist)
{
    __shared__ int cnt[8];
    int t = threadIdx.x;
    if (t < 8) cnt[t] = 0;
    __syncthreads();
    int s = blockIdx.x * 256 + t;
    if (s < NK) {
        int pk = e0e1[s >> 1];
        int e = (s & 1) ? ((pk >> 8) & 255) : (pk & 255);
        atomicAdd(&cnt[e], 1);
    }
    __syncthreads();
    if (t < 8) hist[blockIdx.x * 8 + t] = cnt[t];
}

// ---------------- scan histogram -> per-block bases + used counts ----------------
__global__ __launch_bounds__(256) void scan_kernel(
    const int* __restrict__ hist, int NB, int cap,
    int* __restrict__ base, int* __restrict__ cnt_used)
{
    __shared__ int buf[256];
    int t = threadIdx.x;
    for (int e = 0; e < 8; e++) {
        int v = (t < NB) ? hist[t * 8 + e] : 0;
        int val = v;
        buf[t] = val;
        __syncthreads();
        for (int o = 1; o < 256; o <<= 1) {
            int add = (t >= o) ? buf[t - o] : 0;
            __syncthreads();
            val += add;
            buf[t] = val;
            __syncthreads();
        }
        if (t < NB) base[t * 8 + e] = val - v;     // exclusive prefix
        if (t == 255) cnt_used[e] = min(val, cap); // total, clamped to capacity
        __syncthreads();
    }
}

// ---------------- positions, capacity drop, weight renorm, slot->token maps ----------------
__global__ __launch_bounds__(256) void pos_kernel(
    const int* __restrict__ e0e1, const float2* __restrict__ w01,
    const int* __restrict__ base, int NK, int cap,
    int* __restrict__ tok_of, float* __restrict__ wslot)
{
    __shared__ int waveCnt[4][8];
    __shared__ float kw[256];
    int t = threadIdx.x, lane = t & 63, wave = t >> 6;
    int s = blockIdx.x * 256 + t;
    bool valid = s < NK;
    int e = 8; float w = 0.f;
    if (valid) {
        int pk = e0e1[s >> 1];
        float2 ww = w01[s >> 1];
        if (s & 1) { e = (pk >> 8) & 255; w = ww.y; }
        else       { e = pk & 255;        w = ww.x; }
    }
    unsigned long long mymask = 0ull;
#pragma unroll
    for (int j = 0; j < 8; j++) {
        unsigned long long m = __ballot(e == j);
        if (lane == j) waveCnt[wave][j] = __popcll(m);
        if (e == j) mymask = m;
    }
    __syncthreads();
    int wrank = __popcll(mymask & ((1ull << lane) - 1ull));
    int prior = 0;
    for (int w2 = 0; w2 < wave; w2++) prior += waveCnt[w2][e & 7];
    int pos = base[blockIdx.x * 8 + (e & 7)] + prior + wrank;
    bool keep = valid && (pos < cap);
    kw[t] = keep ? w : 0.f;
    __syncthreads();
    float sum = kw[t] + kw[t ^ 1];      // the 2 slots of a token are adjacent
    float wn = keep ? (kw[t] / (sum + 1e-9f)) : 0.f;
    if (keep) {
        int si = e * cap + pos;
        tok_of[si] = s >> 1;
        wslot[si] = wn;
    }
}

// ---------------- fused expert FFN: y[tok] += w * (GELU(x*W1^T+b1) * W2^T + b2) ----
// One block = 128 expert-rows of one expert. 8 waves; wave owns 16 rows (A in regs).
// 64 chunks of F=32 dff: stage W1c[32x512] + W2c[512x32] (64 KB dbuf, gld_lds with
// XOR-seg swizzle: LDS slot holds global seg (s ^ (row&mask)); read XORs the same) ->
// H = A*W1c^T (32 MFMA) -> GELU -> per-wave LDS bounce (transpose to A-frag layout)
// -> y_acc += H*W2c^T (32 MFMA, 128 f32 acc/lane). Epilogue: weighted y atomics.
// e = blockIdx%8 pins each expert to one XCD so its 4 MB of W lives in that L2.
__global__ __launch_bounds__(512, 2) void fused_ffn_kernel(
    const float* __restrict__ x,
    const unsigned short* __restrict__ W1t,   // [E][DFF][D] bf16
    const float* __restrict__ b1,             // [E][DFF]
    const unsigned short* __restrict__ W2t,   // [E][D][DFF] bf16
    const float* __restrict__ b2,             // [E][D]
    float* __restrict__ y,
    const int* __restrict__ cnt, const int* __restrict__ tok_of,
    const float* __restrict__ wslot, int cap)
{
    __shared__ unsigned short Wb[2][32768];   // [buf][ W1c 16384 | W2c 16384 ] ushorts
    __shared__ unsigned short Hlds[8 * 640];  // per-wave 16 rows x 40 (pad) ushorts

    int b = blockIdx.x;
    int e = b & 7, mtile = b >> 3;
    int m0 = mtile * 128;
    int M = cnt[e];
    if (m0 >= M) return;

    int t = threadIdx.x, lane = t & 63, w = t >> 6;
    int lr = lane & 15, lq = lane >> 4;

    const unsigned short* W1e = W1t + (size_t)e * DFFDIM * DMODEL;
    const unsigned short* W2e = W2t + (size_t)e * DMODEL * DFFDIM;

    // ---- gather A rows (wave w owns rows m0+w*16 .. +16) into bf16 A-frags ----
    int mrowA = m0 + w * 16 + lr;
    int tokA = (mrowA < M) ? tok_of[e * cap + mrowA] : -1;
    const float* xr = x + (size_t)(tokA < 0 ? 0 : tokA) * DMODEL;
    short8 a_frag[16];
#pragma unroll
    for (int kf = 0; kf < 16; kf++) {
        float4 u0 = *(const float4*)(xr + kf * 32 + lq * 8);
        float4 u1 = *(const float4*)(xr + kf * 32 + lq * 8 + 4);
        short8 f;
        f[0] = (short)f2bf(u0.x); f[1] = (short)f2bf(u0.y);
        f[2] = (short)f2bf(u0.z); f[3] = (short)f2bf(u0.w);
        f[4] = (short)f2bf(u1.x); f[5] = (short)f2bf(u1.y);
        f[6] = (short)f2bf(u1.z); f[7] = (short)f2bf(u1.w);
        if (tokA < 0) f = (short8){0, 0, 0, 0, 0, 0, 0, 0};
        a_frag[kf] = f;
    }

    f32x4 yac[32];
#pragma unroll
    for (int j = 0; j < 32; j++) yac[j] = (f32x4){0.f, 0.f, 0.f, 0.f};

    unsigned short* Hl = Hlds + w * 640;
    int l2 = lane >> 2;                               // W2c staging row-within-16
    int w2seg = (((lane & 3) ^ (l2 & 3)) * 8);        // W2c pre-swizzled global seg
    int w1seg = (lane ^ w) * 8;                       // W1c pre-swizzled global seg (f&7 == w)

    // prologue: stage chunk 0 into buffer 0
    {
        int f0 = 0;
#pragma unroll
        for (int q = 0; q < 4; q++) {
            int f = q * 8 + w;
            gld_lds16(W1e + (size_t)(f0 + f) * DMODEL + w1seg,
                      &Wb[0][q * 4096 + w * 512]);
            int n = q * 128 + w * 16 + l2;
            gld_lds16(W2e + (size_t)n * DFFDIM + f0 + w2seg,
                      &Wb[0][16384 + q * 4096 + w * 512]);
        }
    }
    __syncthreads();

    int buf = 0;
    for (int c = 0; c < 64; c++) {
        // stage next chunk into the other buffer (flies under the 64 MFMAs)
        if (c < 63) {
            int f0 = (c + 1) * 32;
#pragma unroll
            for (int q = 0; q < 4; q++) {
                int f = q * 8 + w;
                gld_lds16(W1e + (size_t)(f0 + f) * DMODEL + w1seg,
                          &Wb[buf ^ 1][q * 4096 + w * 512]);
                int n = q * 128 + w * 16 + l2;
                gld_lds16(W2e + (size_t)n * DFFDIM + f0 + w2seg,
                          &Wb[buf ^ 1][16384 + q * 4096 + w * 512]);
            }
        }
        // ---- GEMM1: H[16x32] = A * W1c^T ----
        const unsigned short* W1b = &Wb[buf][0];
        const unsigned short* W2b = &Wb[buf][16384];
        f32x4 h0 = (f32x4){0.f, 0.f, 0.f, 0.f};
        f32x4 h1 = (f32x4){0.f, 0.f, 0.f, 0.f};
#pragma unroll
        for (int kf = 0; kf < 16; kf++) {
            int s6 = ((kf * 4 + lq) ^ (lr & 7)) * 8;
            short8 bf0 = *(const short8*)(W1b + lr * 512 + s6);
            short8 bf1 = *(const short8*)(W1b + (16 + lr) * 512 + s6);
            h0 = __builtin_amdgcn_mfma_f32_16x16x32_bf16(a_frag[kf], bf0, h0, 0, 0, 0);
            h1 = __builtin_amdgcn_mfma_f32_16x16x32_bf16(a_frag[kf], bf1, h1, 0, 0, 0);
        }
        // ---- GELU(+b1) and per-wave LDS bounce into A-frag layout ----
        int f0 = c * 32;
        float b1v0 = b1[e * DFFDIM + f0 + lr];
        float b1v1 = b1[e * DFFDIM + f0 + 16 + lr];
#pragma unroll
        for (int r = 0; r < 4; r++) {
            float v0 = h0[r] + b1v0;
            v0 = 0.5f * v0 * (1.0f + erff(v0 * 0.7071067811865475f));
            float v1 = h1[r] + b1v1;
            v1 = 0.5f * v1 * (1.0f + erff(v1 * 0.7071067811865475f));
            Hl[(lq * 4 + r) * 40 + lr] = f2bf(v0);
            Hl[(lq * 4 + r) * 40 + 16 + lr] = f2bf(v1);
        }
        short8 a2 = *(const short8*)(Hl + lr * 40 + lq * 8);   // row lr, dff lq*8..+8
        // ---- GEMM2: y_acc += H * W2c^T ----
#pragma unroll
        for (int j = 0; j < 32; j++) {
            short8 b2f = *(const short8*)(W2b + (16 * j + lr) * 32 + ((lq ^ (lr & 3)) * 8));
            yac[j] = __builtin_amdgcn_mfma_f32_16x16x32_bf16(a2, b2f, yac[j], 0, 0, 0);
        }
        __syncthreads();   // drains vmcnt(0): next buffer staged; buf reads done
        buf ^= 1;
    }

    // ---- epilogue: y[tok] += w * (acc + b2); C layout col=lr(n), row=lq*4+r(m) ----
    int tokC[4]; float wC[4];
#pragma unroll
    for (int r = 0; r < 4; r++) {
        int m = m0 + w * 16 + lq * 4 + r;
        if (m < M) { tokC[r] = tok_of[e * cap + m]; wC[r] = wslot[e * cap + m]; }
        else       { tokC[r] = -1; wC[r] = 0.f; }
    }
#pragma unroll
    for (int j = 0; j < 32; j++) {
        int n = 16 * j + lr;
        float b2v = b2[e * DMODEL + n];
        f32x4 v = yac[j];
#pragma unroll
        for (int r = 0; r < 4; r++) {
            if (tokC[r] >= 0)
                atomicAdd(y + (size_t)tokC[r] * DMODEL + n, wC[r] * (v[r] + b2v));
        }
    }
}

extern "C" void kernel_launch(void* const* d_in, const int* in_sizes, int n_in,
                              void* d_out, int out_size, void* d_ws, size_t ws_size,
                              hipStream_t stream)
{
    const float* x  = (const float*)d_in[0];
    const float* Wr = (const float*)d_in[1];
    const float* br = (const float*)d_in[2];
    const float* W1 = (const float*)d_in[3];
    const float* b1 = (const float*)d_in[4];
    const float* W2 = (const float*)d_in[5];
    const float* b2 = (const float*)d_in[6];
    float* y = (float*)d_out;
    (void)n_in; (void)ws_size;

    const int N = in_sizes[0] / DMODEL;            // 32768 tokens
    const int NK = N * TOPK;                       // 65536 slots
    const int cap = (NK * 5 + 31) / 32;            // ceil(1.25*NK/8) = 10240
    const int NB = (NK + 255) / 256;               // 256
    const int mT = cap / 128;                      // 80 m-tiles per expert

    char* ws = (char*)d_ws;
    size_t off = 0;
    auto take = [&](size_t bytes) {
        char* p = ws + off;
        off = (off + bytes + 255) & ~(size_t)255;
        return p;
    };
    unsigned short* W1t = (unsigned short*)take((size_t)E_EXP * DMODEL * DFFDIM * 2); // [E][DFF][D]
    unsigned short* W2t = (unsigned short*)take((size_t)E_EXP * DMODEL * DFFDIM * 2); // [E][D][DFF]
    int*    e0e1 = (int*)take((size_t)N * 4);
    float2* w01  = (float2*)take((size_t)N * 8);
    int*    hist = (int*)take((size_t)NB * 8 * 4);
    int*    base = (int*)take((size_t)NB * 8 * 4);
    int*    cnt  = (int*)take(64);
    int*    tok_of = (int*)take((size_t)E_EXP * cap * 4);
    float*  wslot  = (float*)take((size_t)E_EXP * cap * 4);

    transpose_kernel<<<dim3(DFFDIM / 32, DMODEL / 32, E_EXP), dim3(32, 8), 0, stream>>>(W1, W1t, DMODEL, DFFDIM);
    transpose_kernel<<<dim3(DMODEL / 32, DFFDIM / 32, E_EXP), dim3(32, 8), 0, stream>>>(W2, W2t, DFFDIM, DMODEL);
    router_kernel<<<(N + 3) / 4, 256, 0, stream>>>(x, Wr, br, N, e0e1, w01);
    hist_kernel<<<NB, 256, 0, stream>>>(e0e1, NK, hist);
    scan_kernel<<<1, 256, 0, stream>>>(hist, NB, cap, base, cnt);
    pos_kernel<<<NB, 256, 0, stream>>>(e0e1, w01, base, NK, cap, tok_of, wslot);
    hipMemsetAsync(d_out, 0, (size_t)out_size * 4, stream);

    fused_ffn_kernel<<<E_EXP * mT, 512, 0, stream>>>(
        x, W1t, b1, W2t, b2, y, cnt, tok_of, wslot, cap);
}

// Round 6
// 1061.263 us; speedup vs baseline: 1.3834x; 1.0125x over previous
//
#include <hip/hip_runtime.h>
#include <cstdint>
#include <cstddef>

#define E_EXP 8
#define TOPK 2
#define DMODEL 512
#define DFFDIM 2048

typedef __attribute__((ext_vector_type(8))) short short8;
typedef __attribute__((ext_vector_type(4))) float f32x4;

__device__ __forceinline__ unsigned short f2bf(float f) {
    unsigned int u = __float_as_uint(f);
    u += 0x7fffu + ((u >> 16) & 1u);   // round-to-nearest-even
    return (unsigned short)(u >> 16);
}

// async global->LDS, 16B per lane. LDS dest MUST be wave-uniform; HW writes lane i
// at base + i*16 (m104). Caller passes an in-bounds, wave-uniform LDS pointer.
__device__ __forceinline__ void gld_lds16(const unsigned short* g, unsigned short* l) {
    __builtin_amdgcn_global_load_lds(
        (const __attribute__((address_space(1))) void*)g,
        (__attribute__((address_space(3))) void*)l, 16, 0, 0);
}

// ---------------- weight transpose + fp32->bf16 convert ----------------
// in: [E][R][C] fp32  ->  out: [E][C][R] bf16
__global__ __launch_bounds__(256) void transpose_kernel(
    const float* __restrict__ in, unsigned short* __restrict__ out, int R, int C)
{
    __shared__ float tile[32][33];
    const float* ie = in + (size_t)blockIdx.z * R * C;
    unsigned short* oe = out + (size_t)blockIdx.z * R * C;
    int x = blockIdx.x * 32 + threadIdx.x;
#pragma unroll
    for (int i = 0; i < 4; i++) {
        int ry = blockIdx.y * 32 + threadIdx.y + i * 8;
        tile[threadIdx.y + i * 8][threadIdx.x] = ie[(size_t)ry * C + x];
    }
    __syncthreads();
    int xo = blockIdx.y * 32 + threadIdx.x;
#pragma unroll
    for (int i = 0; i < 4; i++) {
        int co = blockIdx.x * 32 + threadIdx.y + i * 8;
        oe[(size_t)co * R + xo] = f2bf(tile[threadIdx.x][threadIdx.y + i * 8]);
    }
}

// ---------------- router: logits -> softmax -> top2 -> weights ----------------
__global__ __launch_bounds__(256) void router_kernel(
    const float* __restrict__ x, const float* __restrict__ Wr,
    const float* __restrict__ br, int N,
    int* __restrict__ e0e1, float2* __restrict__ w01)
{
    int lane = threadIdx.x & 63, wave = threadIdx.x >> 6;
    int t = blockIdx.x * 4 + wave;
    if (t >= N) return;
    const float* xr = x + (size_t)t * DMODEL;
    float4 v0 = *(const float4*)(xr + lane * 4);
    float4 v1 = *(const float4*)(xr + 256 + lane * 4);
    float xv[8] = {v0.x, v0.y, v0.z, v0.w, v1.x, v1.y, v1.z, v1.w};
    const float* wr0 = Wr + (size_t)lane * 32;             // rows lane*4 .. +3
    const float* wr1 = Wr + (size_t)(256 + lane * 4) * 8;  // rows 256+lane*4 .. +3
    double acc[8];
#pragma unroll
    for (int j = 0; j < 8; j++) acc[j] = 0.0;
#pragma unroll
    for (int c = 0; c < 4; c++) {
#pragma unroll
        for (int j = 0; j < 8; j++) {
            acc[j] += (double)xv[c] * (double)wr0[c * 8 + j];
            acc[j] += (double)xv[4 + c] * (double)wr1[c * 8 + j];
        }
    }
#pragma unroll
    for (int j = 0; j < 8; j++) {
        double s = acc[j];
#pragma unroll
        for (int o = 32; o > 0; o >>= 1) s += __shfl_xor(s, o, 64);
        acc[j] = s;
    }
    if (lane == 0) {
        float l[8], p[8];
        float mx = -1e30f;
        for (int j = 0; j < 8; j++) { l[j] = (float)acc[j] + br[j]; mx = fmaxf(mx, l[j]); }
        float Z = 0.f;
        for (int j = 0; j < 8; j++) { p[j] = expf(l[j] - mx); Z += p[j]; }
        for (int j = 0; j < 8; j++) p[j] /= Z;
        int e0 = 0;
        for (int j = 1; j < 8; j++) if (l[j] > l[e0]) e0 = j;        // ties -> lower idx
        int e1 = (e0 == 0) ? 1 : 0;
        for (int j = 0; j < 8; j++) if (j != e0 && l[j] > l[e1]) e1 = j;
        float den = p[e0] + p[e1] + 1e-9f;
        e0e1[t] = e0 | (e1 << 8);
        w01[t] = make_float2(p[e0] / den, p[e1] / den);
    }
}

// ---------------- per-block expert histogram (slot order) ----------------
__global__ __launch_bounds__(256) void hist_kernel(
    const int* __restrict__ e0e1, int NK, int* __restrict__ hist)
{
    __shared__ int cnt[8];
    int t = threadIdx.x;
    if (t < 8) cnt[t] = 0;
    __syncthreads();
    int s = blockIdx.x * 256 + t;
    if (s < NK) {
        int pk = e0e1[s >> 1];
        int e = (s & 1) ? ((pk >> 8) & 255) : (pk & 255);
        atomicAdd(&cnt[e], 1);
    }
    __syncthreads();
    if (t < 8) hist[blockIdx.x * 8 + t] = cnt[t];
}

// ---------------- scan histogram -> per-block bases + used counts ----------------
__global__ __launch_bounds__(256) void scan_kernel(
    const int* __restrict__ hist, int NB, int cap,
    int* __restrict__ base, int* __restrict__ cnt_used)
{
    __shared__ int buf[256];
    int t = threadIdx.x;
    for (int e = 0; e < 8; e++) {
        int v = (t < NB) ? hist[t * 8 + e] : 0;
        int val = v;
        buf[t] = val;
        __syncthreads();
        for (int o = 1; o < 256; o <<= 1) {
            int add = (t >= o) ? buf[t - o] : 0;
            __syncthreads();
            val += add;
            buf[t] = val;
            __syncthreads();
        }
        if (t < NB) base[t * 8 + e] = val - v;     // exclusive prefix
        if (t == 255) cnt_used[e] = min(val, cap); // total, clamped to capacity
        __syncthreads();
    }
}

// ---------------- positions, capacity drop, weight renorm, slot->token maps ----------------
__global__ __launch_bounds__(256) void pos_kernel(
    const int* __restrict__ e0e1, const float2* __restrict__ w01,
    const int* __restrict__ base, int NK, int cap,
    int* __restrict__ tok_of, float* __restrict__ wslot)
{
    __shared__ int waveCnt[4][8];
    __shared__ float kw[256];
    int t = threadIdx.x, lane = t & 63, wave = t >> 6;
    int s = blockIdx.x * 256 + t;
    bool valid = s < NK;
    int e = 8; float w = 0.f;
    if (valid) {
        int pk = e0e1[s >> 1];
        float2 ww = w01[s >> 1];
        if (s & 1) { e = (pk >> 8) & 255; w = ww.y; }
        else       { e = pk & 255;        w = ww.x; }
    }
    unsigned long long mymask = 0ull;
#pragma unroll
    for (int j = 0; j < 8; j++) {
        unsigned long long m = __ballot(e == j);
        if (lane == j) waveCnt[wave][j] = __popcll(m);
        if (e == j) mymask = m;
    }
    __syncthreads();
    int wrank = __popcll(mymask & ((1ull << lane) - 1ull));
    int prior = 0;
    for (int w2 = 0; w2 < wave; w2++) prior += waveCnt[w2][e & 7];
    int pos = base[blockIdx.x * 8 + (e & 7)] + prior + wrank;
    bool keep = valid && (pos < cap);
    kw[t] = keep ? w : 0.f;
    __syncthreads();
    float sum = kw[t] + kw[t ^ 1];      // the 2 slots of a token are adjacent
    float wn = keep ? (kw[t] / (sum + 1e-9f)) : 0.f;
    if (keep) {
        int si = e * cap + pos;
        tok_of[si] = s >> 1;
        wslot[si] = wn;
    }
}

// ---------------- fused expert FFN: y[tok] += w * (GELU(x*W1^T+b1) * W2^T + b2) ----
// Block = 128 expert-rows of expert e = blockIdx&7 (XCD-pinned: 4MB weights L2-hot).
// 8 waves x 16 rows; A in regs (64 VGPR); 64 chunks of F=32 dff.
// SINGLE-buffered W1s/W2s (64 KB) + staggered staging:
//   GEMM1(c) | barA | stage W1[c+1] | GELU+pack+GEMM2(c) | barB | stage W2[c+1]
// each __syncthreads' implicit vmcnt(0) drains the stage issued one phase earlier,
// so every stage flies under a compute phase (T3-minimum, m248).
// GEMM1 uses PAIRED dff rows (bf0=row 2lr, bf1=row 2lr+1) so the GELU'd pair packs
// into one b32 LDS write (stride-20 u32 rows: 2 lanes/bank = free; r5's b16 bounce
// was the 6.9e7-conflict source). W1s/W2s XOR-seg swizzle: LDS (row,pos) holds
// global seg pos^(row&7) [W1] / pos^(row&3) [W2]; staging pre-swizzles the GLOBAL
// source (dest HW-linear), reads XOR the same key (rule #21).
__global__ __launch_bounds__(512, 2) void fused_ffn_kernel(
    const float* __restrict__ x,
    const unsigned short* __restrict__ W1t,   // [E][DFF][D] bf16
    const float* __restrict__ b1,             // [E][DFF]
    const unsigned short* __restrict__ W2t,   // [E][D][DFF] bf16
    const float* __restrict__ b2,             // [E][D]
    float* __restrict__ y,
    const int* __restrict__ cnt, const int* __restrict__ tok_of,
    const float* __restrict__ wslot, int cap)
{
    __shared__ unsigned short W1s[16384];     // 32 KB: [32 f][512 k] (chunk c)
    __shared__ unsigned short W2s[16384];     // 32 KB: [512 n][32 dff]
    __shared__ unsigned int   Hb[8 * 320];    // 10 KB: per-wave [16 m][20 u32]

    int b = blockIdx.x;
    int e = b & 7, mtile = b >> 3;
    int m0 = mtile * 128;
    int M = cnt[e];
    if (m0 >= M) return;

    int t = threadIdx.x, lane = t & 63, w = t >> 6;
    int lr = lane & 15, lq = lane >> 4;

    const unsigned short* W1e = W1t + (size_t)e * DFFDIM * DMODEL;
    const unsigned short* W2e = W2t + (size_t)e * DMODEL * DFFDIM;

    // ---- gather A rows (wave w owns rows m0+w*16 .. +16) into bf16 A-frags ----
    int mrowA = m0 + w * 16 + lr;
    int tokA = (mrowA < M) ? tok_of[e * cap + mrowA] : -1;
    const float* xr = x + (size_t)(tokA < 0 ? 0 : tokA) * DMODEL;
    short8 a_frag[16];
#pragma unroll
    for (int kf = 0; kf < 16; kf++) {
        float4 u0 = *(const float4*)(xr + kf * 32 + lq * 8);
        float4 u1 = *(const float4*)(xr + kf * 32 + lq * 8 + 4);
        short8 f;
        f[0] = (short)f2bf(u0.x); f[1] = (short)f2bf(u0.y);
        f[2] = (short)f2bf(u0.z); f[3] = (short)f2bf(u0.w);
        f[4] = (short)f2bf(u1.x); f[5] = (short)f2bf(u1.y);
        f[6] = (short)f2bf(u1.z); f[7] = (short)f2bf(u1.w);
        if (tokA < 0) f = (short8){0, 0, 0, 0, 0, 0, 0, 0};
        a_frag[kf] = f;
    }

    f32x4 yac[32];
#pragma unroll
    for (int j = 0; j < 32; j++) yac[j] = (f32x4){0.f, 0.f, 0.f, 0.f};

    int wofs = __builtin_amdgcn_readfirstlane(w * 512);
    // staging sources (chunk 0, q 0); W1 row advances 32/chunk, W2 dff 32/chunk
    const unsigned short* gW1 = W1e + (size_t)w * DMODEL + (size_t)(lane ^ w) * 8;
    const unsigned short* gW2 = W2e + (size_t)(w * 16 + (lane >> 2)) * DFFDIM
                                    + (size_t)((lane & 3) ^ ((lane >> 2) & 3)) * 8;

    // prologue: stage chunk 0
#pragma unroll
    for (int q = 0; q < 4; q++) {
        gld_lds16(gW1 + (size_t)q * 4096,   W1s + q * 4096 + wofs);
        gld_lds16(gW2 + (size_t)q * 262144, W2s + q * 4096 + wofs);
    }
    __syncthreads();

    const unsigned short* W1r0 = W1s + (2 * lr) * 512;
    int s1a = (2 * lr) & 7, s1b = s1a | 1;
    unsigned int* Hw = Hb + w * 320;
    const unsigned short* Hu = (const unsigned short*)(Hb + w * 320 + lr * 20) + lq * 8;
    const unsigned short* W2r = W2s + lr * 32 + ((lq ^ (lr & 3)) * 8);

    for (int c = 0; c < 64; c++) {
        // ---- GEMM1: H-pair (dff 2lr, 2lr+1) = A * W1c^T ----
        f32x4 h0 = (f32x4){0.f, 0.f, 0.f, 0.f};
        f32x4 h1 = (f32x4){0.f, 0.f, 0.f, 0.f};
#pragma unroll
        for (int kf = 0; kf < 16; kf++) {
            int k4 = kf * 4 + lq;
            short8 bf0 = *(const short8*)(W1r0 + ((k4 ^ s1a) * 8));
            short8 bf1 = *(const short8*)(W1r0 + 512 + ((k4 ^ s1b) * 8));
            h0 = __builtin_amdgcn_mfma_f32_16x16x32_bf16(a_frag[kf], bf0, h0, 0, 0, 0);
            h1 = __builtin_amdgcn_mfma_f32_16x16x32_bf16(a_frag[kf], bf1, h1, 0, 0, 0);
        }
        __syncthreads();              // barA: W1s reads done; drains W2[c] stage
        if (c < 63) {                 // stage W1[c+1] under GELU+GEMM2
            const unsigned short* g1 = gW1 + (size_t)(c + 1) * 16384;
#pragma unroll
            for (int q = 0; q < 4; q++)
                gld_lds16(g1 + (size_t)q * 4096, W1s + q * 4096 + wofs);
        }
        // ---- GELU(+b1) and packed b32 bounce (conflict-free stride-20 rows) ----
        {
            float2 b1v = *(const float2*)(b1 + e * DFFDIM + c * 32 + 2 * lr);
#pragma unroll
            for (int r = 0; r < 4; r++) {
                float v0 = h0[r] + b1v.x;
                v0 = 0.5f * v0 * (1.0f + erff(v0 * 0.7071067811865475f));
                float v1 = h1[r] + b1v.y;
                v1 = 0.5f * v1 * (1.0f + erff(v1 * 0.7071067811865475f));
                Hw[(lq * 4 + r) * 20 + lr] =
                    (unsigned int)f2bf(v0) | ((unsigned int)f2bf(v1) << 16);
            }
        }
        short8 a2 = *(const short8*)Hu;   // row lr, dff lq*8..+8 (wave-private)
        // ---- GEMM2: y_acc += H * W2c^T ----
#pragma unroll
        for (int j = 0; j < 32; j++) {
            short8 b2f = *(const short8*)(W2r + j * 512);
            yac[j] = __builtin_amdgcn_mfma_f32_16x16x32_bf16(a2, b2f, yac[j], 0, 0, 0);
        }
        __syncthreads();              // barB: W2s reads done; drains W1[c+1] stage
        if (c < 63) {                 // stage W2[c+1] under next GEMM1
            const unsigned short* g2 = gW2 + (size_t)(c + 1) * 32;
#pragma unroll
            for (int q = 0; q < 4; q++)
                gld_lds16(g2 + (size_t)q * 262144, W2s + q * 4096 + wofs);
        }
    }

    // ---- epilogue: y[tok] += w * (acc + b2); C layout col=lr(n), row=lq*4+r(m) ----
    int tokC[4]; float wC[4];
#pragma unroll
    for (int r = 0; r < 4; r++) {
        int m = m0 + w * 16 + lq * 4 + r;
        if (m < M) { tokC[r] = tok_of[e * cap + m]; wC[r] = wslot[e * cap + m]; }
        else       { tokC[r] = -1; wC[r] = 0.f; }
    }
#pragma unroll
    for (int j = 0; j < 32; j++) {
        int n = 16 * j + lr;
        float b2v = b2[e * DMODEL + n];
        f32x4 v = yac[j];
#pragma unroll
        for (int r = 0; r < 4; r++) {
            if (tokC[r] >= 0)
                atomicAdd(y + (size_t)tokC[r] * DMODEL + n, wC[r] * (v[r] + b2v));
        }
    }
}

extern "C" void kernel_launch(void* const* d_in, const int* in_sizes, int n_in,
                              void* d_out, int out_size, void* d_ws, size_t ws_size,
                              hipStream_t stream)
{
    const float* x  = (const float*)d_in[0];
    const float* Wr = (const float*)d_in[1];
    const float* br = (const float*)d_in[2];
    const float* W1 = (const float*)d_in[3];
    const float* b1 = (const float*)d_in[4];
    const float* W2 = (const float*)d_in[5];
    const float* b2 = (const float*)d_in[6];
    float* y = (float*)d_out;
    (void)n_in; (void)ws_size;

    const int N = in_sizes[0] / DMODEL;            // 32768 tokens
    const int NK = N * TOPK;                       // 65536 slots
    const int cap = (NK * 5 + 31) / 32;            // ceil(1.25*NK/8) = 10240
    const int NB = (NK + 255) / 256;               // 256
    const int mT = cap / 128;                      // 80 m-tiles per expert

    char* ws = (char*)d_ws;
    size_t off = 0;
    auto take = [&](size_t bytes) {
        char* p = ws + off;
        off = (off + bytes + 255) & ~(size_t)255;
        return p;
    };
    unsigned short* W1t = (unsigned short*)take((size_t)E_EXP * DMODEL * DFFDIM * 2); // [E][DFF][D]
    unsigned short* W2t = (unsigned short*)take((size_t)E_EXP * DMODEL * DFFDIM * 2); // [E][D][DFF]
    int*    e0e1 = (int*)take((size_t)N * 4);
    float2* w01  = (float2*)take((size_t)N * 8);
    int*    hist = (int*)take((size_t)NB * 8 * 4);
    int*    base = (int*)take((size_t)NB * 8 * 4);
    int*    cnt  = (int*)take(64);
    int*    tok_of = (int*)take((size_t)E_EXP * cap * 4);
    float*  wslot  = (float*)take((size_t)E_EXP * cap * 4);

    transpose_kernel<<<dim3(DFFDIM / 32, DMODEL / 32, E_EXP), dim3(32, 8), 0, stream>>>(W1, W1t, DMODEL, DFFDIM);
    transpose_kernel<<<dim3(DMODEL / 32, DFFDIM / 32, E_EXP), dim3(32, 8), 0, stream>>>(W2, W2t, DFFDIM, DMODEL);
    router_kernel<<<(N + 3) / 4, 256, 0, stream>>>(x, Wr, br, N, e0e1, w01);
    hist_kernel<<<NB, 256, 0, stream>>>(e0e1, NK, hist);
    scan_kernel<<<1, 256, 0, stream>>>(hist, NB, cap, base, cnt);
    pos_kernel<<<NB, 256, 0, stream>>>(e0e1, w01, base, NK, cap, tok_of, wslot);
    hipMemsetAsync(d_out, 0, (size_t)out_size * 4, stream);

    fused_ffn_kernel<<<E_EXP * mT, 512, 0, stream>>>(
        x, W1t, b1, W2t, b2, y, cnt, tok_of, wslot, cap);
}